// Round 2
// baseline (1208.570 us; speedup 1.0000x reference)
//
#include <hip/hip_runtime.h>

// Problem constants (fixed by setup_inputs)
#define Bsz 4
#define Cc  512
#define C2  1024
#define H0c 192
#define Hh  48
#define Nn  2304   // 48*48
#define HNh 8
#define HD  64
#define Hs  25
#define Ms  625    // 25*25

typedef const float* fp;

// ---------------- K1: stride-4 nearest downsample ----------------
__global__ __launch_bounds__(256) void k_downsample(fp __restrict__ x,
                                                    float* __restrict__ xds) {
    int idx = blockIdx.x * 256 + threadIdx.x;            // < B*C*2304
    if (idx >= Bsz * Cc * Nn) return;
    int j  = idx % Hh;
    int i  = (idx / Hh) % Hh;
    int bc = idx / Nn;
    xds[idx] = x[((size_t)bc * H0c + i * 4) * H0c + j * 4];
}

// ---------------- K2/K4/K6: GEMM  Y[b][o][n] = sum_c W[o][c]*X[b][c][n], fused bias/BN ---
// 128x128 tile, 256 threads, 8x8 per thread, K=512 staged 16 at a time.
__global__ __launch_bounds__(256) void k_gemm(
    fp __restrict__ W, const float* __restrict__ X, float* __restrict__ Y,
    int Md, int Nd,
    fp __restrict__ bias,
    fp __restrict__ bn_g, fp __restrict__ bn_b, fp __restrict__ bn_m, fp __restrict__ bn_v)
{
    const int K = 512;
    __shared__ float sA[16][132];   // [kk][mm]
    __shared__ float sB[16][132];   // [kk][nn]
    int b  = blockIdx.z;
    int m0 = blockIdx.y * 128, n0 = blockIdx.x * 128;
    int t  = threadIdx.x, tx = t & 15, ty = t >> 4;
    const float* Xb = X + (size_t)b * K * Nd;
    float acc[8][8] = {};
    for (int k0 = 0; k0 < K; k0 += 16) {
        {   // A: 128m x 16k ; W rows are k-contiguous
            int mm = t >> 1, kk0 = (t & 1) * 8;
            fp wr = W + (size_t)(m0 + mm) * K + k0 + kk0;
            #pragma unroll
            for (int i = 0; i < 8; i++) sA[kk0 + i][mm] = wr[i];
        }
        {   // B: 16k x 128n ; f32 rows n-contiguous
            int kk = t >> 4, nn0 = tx * 8;
            const float* xr = Xb + (size_t)(k0 + kk) * Nd + n0 + nn0;
            #pragma unroll
            for (int i = 0; i < 8; i++) sB[kk][nn0 + i] = (n0 + nn0 + i < Nd) ? xr[i] : 0.f;
        }
        __syncthreads();
        #pragma unroll
        for (int kk = 0; kk < 16; kk++) {
            float4 a0 = *(const float4*)&sA[kk][ty * 8];
            float4 a1 = *(const float4*)&sA[kk][ty * 8 + 4];
            float4 b0 = *(const float4*)&sB[kk][tx * 8];
            float4 b1 = *(const float4*)&sB[kk][tx * 8 + 4];
            float a[8] = {a0.x, a0.y, a0.z, a0.w, a1.x, a1.y, a1.z, a1.w};
            float bb[8] = {b0.x, b0.y, b0.z, b0.w, b1.x, b1.y, b1.z, b1.w};
            #pragma unroll
            for (int i = 0; i < 8; i++)
                #pragma unroll
                for (int j = 0; j < 8; j++) acc[i][j] += a[i] * bb[j];
        }
        __syncthreads();
    }
    #pragma unroll
    for (int i = 0; i < 8; i++) {
        int o = m0 + ty * 8 + i;
        float addb = bias ? bias[o] : 0.f;
        float sc = 1.f, sh = 0.f;
        if (bn_g) {
            sc = bn_g[o] * rsqrtf(bn_v[o] + 1e-5f);
            sh = bn_b[o] - bn_m[o] * sc;
        }
        float* yr = Y + ((size_t)b * Md + o) * Nd;
        #pragma unroll
        for (int j = 0; j < 8; j++) {
            int n = n0 + tx * 8 + j;
            if (n < Nd) yr[n] = (acc[i][j] + addb) * sc + sh;
        }
    }
}

// ---------------- K3: 2x2 dwconv s2 p1 + BN + ReLU ----------------
__global__ __launch_bounds__(256) void k_sr1(const float* __restrict__ xds, fp __restrict__ w,
                                             fp g, fp bb, fp bm, fp bv,
                                             float* __restrict__ kv1) {
    int idx = blockIdx.x * 256 + threadIdx.x;    // < B*C*625
    if (idx >= Bsz * Cc * Ms) return;
    int wo = idx % Hs, ho = (idx / Hs) % Hs, bc = idx / Ms;
    int c = bc % Cc;
    const float* src = xds + (size_t)bc * Nn;
    float acc = 0.f;
    #pragma unroll
    for (int di = 0; di < 2; di++) {
        int ih = ho * 2 - 1 + di;
        if (ih < 0 || ih >= Hh) continue;
        #pragma unroll
        for (int dj = 0; dj < 2; dj++) {
            int iw = wo * 2 - 1 + dj;
            if (iw < 0 || iw >= Hh) continue;
            acc += w[c * 4 + di * 2 + dj] * src[ih * Hh + iw];
        }
    }
    float sc = g[c] * rsqrtf(bv[c] + 1e-5f);
    float y = (acc - bm[c]) * sc + bb[c];
    kv1[idx] = fmaxf(y, 0.f);
}

// ---------------- K5: 3x3 dwconv s1 p1 + bias + residual ----------------
__global__ __launch_bounds__(256) void k_lc(const float* __restrict__ kv2, fp __restrict__ w,
                                            fp __restrict__ lb, float* __restrict__ kv3) {
    int idx = blockIdx.x * 256 + threadIdx.x;    // < B*C*625
    if (idx >= Bsz * Cc * Ms) return;
    int wo = idx % Hs, ho = (idx / Hs) % Hs, bc = idx / Ms;
    int c = bc % Cc;
    const float* src = kv2 + (size_t)bc * Ms;
    float acc = 0.f;
    #pragma unroll
    for (int di = 0; di < 3; di++) {
        int ih = ho - 1 + di;
        if (ih < 0 || ih >= Hs) continue;
        #pragma unroll
        for (int dj = 0; dj < 3; dj++) {
            int iw = wo - 1 + dj;
            if (iw < 0 || iw >= Hs) continue;
            acc += w[c * 9 + di * 3 + dj] * src[ih * Hs + iw];
        }
    }
    kv3[idx] = acc + lb[c] + src[ho * Hs + wo];
}

// ---------------- K7: flash-style attention ----------------
// qbuf [b][c][n] f32, kvp [b][2C][m] f32 (k then v) -> Obuf [b][c][n] f32
// Block: 256 thr, 64 rows (n) per block, chunks of 64 m, online softmax.
__global__ __launch_bounds__(256) void k_attn(const float* __restrict__ qbuf,
                                              const float* __restrict__ kvp,
                                              float* __restrict__ Obuf) {
    __shared__ float qs[64][68];      // [d][r]
    __shared__ float ks[64][68];      // [d][m] during scores; reused as P[m][r] after barrier
    __shared__ float vs[64][68];      // [m][d]
    __shared__ float redmax[64][17];
    __shared__ float redsum[64][17];
    __shared__ float rowm[64], rowl[64];

    int bh = blockIdx.y;              // 0..31
    int b = bh >> 3, h = bh & 7;
    int n0 = blockIdx.x * 64;
    const float* qb = qbuf + ((size_t)(b * Cc + h * HD)) * Nn;
    const float* kb = kvp + ((size_t)(b * C2 + h * HD)) * Ms;
    const float* vb = kvp + ((size_t)(b * C2 + Cc + h * HD)) * Ms;

    int t = threadIdx.x;
    int rg = t >> 4, mj = t & 15;

    for (int i = t; i < 64 * 64; i += 256) {     // q tile: coalesced over n
        int r = i & 63, d = i >> 6;
        qs[d][r] = qb[(size_t)d * Nn + n0 + r];
    }
    if (t < 64) { rowm[t] = -1e30f; rowl[t] = 0.f; }
    float Oacc[4][4] = {};
    __syncthreads();

    for (int mc = 0; mc < Ms; mc += 64) {
        int mlen = min(64, Ms - mc);
        for (int i = t; i < 64 * 64; i += 256) { // stage k [d][m], v^T [m][d]
            int m = i & 63, d = i >> 6;
            float kvv = 0.f, vvv = 0.f;
            if (m < mlen) {
                kvv = kb[(size_t)d * Ms + mc + m];
                vvv = vb[(size_t)d * Ms + mc + m];
            }
            ks[d][m] = kvv;
            vs[m][d] = vvv;
        }
        __syncthreads();                                   // [A]
        // ---- scores (reads qs, ks) ----
        float s[4][4] = {};
        for (int d = 0; d < 64; d++) {
            float4 qv = *(const float4*)&qs[d][rg * 4];
            float4 kv = *(const float4*)&ks[d][mj * 4];
            float qa[4] = {qv.x, qv.y, qv.z, qv.w};
            float ka[4] = {kv.x, kv.y, kv.z, kv.w};
            #pragma unroll
            for (int rr = 0; rr < 4; rr++)
                #pragma unroll
                for (int jm = 0; jm < 4; jm++) s[rr][jm] += qa[rr] * ka[jm];
        }
        #pragma unroll
        for (int rr = 0; rr < 4; rr++) {
            float lm = -1e30f;
            #pragma unroll
            for (int jm = 0; jm < 4; jm++) {
                s[rr][jm] *= 0.125f;
                if (4 * mj + jm >= mlen) s[rr][jm] = -1e30f;
                lm = fmaxf(lm, s[rr][jm]);
            }
            redmax[4 * rg + rr][mj] = lm;
        }
        __syncthreads();                                   // [B] all ks reads done
        float alpha[4], mnew_[4];
        #pragma unroll
        for (int rr = 0; rr < 4; rr++) {
            int r = 4 * rg + rr;
            float cm = redmax[r][0];
            #pragma unroll
            for (int u = 1; u < 16; u++) cm = fmaxf(cm, redmax[r][u]);
            float mold = rowm[r];
            float mnew = fmaxf(mold, cm);
            mnew_[rr] = mnew;
            alpha[rr] = __expf(mold - mnew);
            float ps = 0.f;
            #pragma unroll
            for (int jm = 0; jm < 4; jm++) {
                float p = __expf(s[rr][jm] - mnew);
                s[rr][jm] = p;
                ps += p;
            }
            redsum[r][mj] = ps;
        }
        #pragma unroll
        for (int jm = 0; jm < 4; jm++) {                   // P[m][r] aliases ks (safe after [B])
            float4 pv = make_float4(s[0][jm], s[1][jm], s[2][jm], s[3][jm]);
            *(float4*)&ks[4 * mj + jm][4 * rg] = pv;
        }
        __syncthreads();                                   // [C]
        #pragma unroll
        for (int rr = 0; rr < 4; rr++) {
            int r = 4 * rg + rr;
            float cs = 0.f;
            #pragma unroll
            for (int u = 0; u < 16; u++) cs += redsum[r][u];
            if (mj == 0) {
                rowl[r] = rowl[r] * alpha[rr] + cs;
                rowm[r] = mnew_[rr];
            }
            #pragma unroll
            for (int j = 0; j < 4; j++) Oacc[rr][j] *= alpha[rr];
        }
        for (int m = 0; m < mlen; m++) {                   // O += P * V
            float4 pv = *(const float4*)&ks[m][rg * 4];
            float4 vv = *(const float4*)&vs[m][mj * 4];
            float pa[4] = {pv.x, pv.y, pv.z, pv.w};
            float va[4] = {vv.x, vv.y, vv.z, vv.w};
            #pragma unroll
            for (int rr = 0; rr < 4; rr++)
                #pragma unroll
                for (int j = 0; j < 4; j++) Oacc[rr][j] += pa[rr] * va[j];
        }
        __syncthreads();                                   // [D]
    }
    #pragma unroll
    for (int rr = 0; rr < 4; rr++) {
        int r = 4 * rg + rr;
        float inv = 1.f / rowl[r];
        int n = n0 + r;
        #pragma unroll
        for (int j = 0; j < 4; j++) {
            int d = 4 * mj + j;
            Obuf[((size_t)(b * Cc + h * HD + d)) * Nn + n] = Oacc[rr][j] * inv;
        }
    }
}

// ---------------- K8: 4x nearest upsample, f32 -> f32, float4 stores ----------------
// Output groups of 4 cols share one src value; one lane = one float4 store.
__global__ __launch_bounds__(256) void k_upsample(const float* __restrict__ O,
                                                  float* __restrict__ out) {
    size_t idx = (size_t)blockIdx.x * 256 + threadIdx.x;   // < B*C*192*48
    if (idx >= (size_t)Bsz * Cc * H0c * 48) return;
    int jg = (int)(idx % 48);
    int i  = (int)((idx / 48) % H0c);
    int bc = (int)(idx / ((size_t)48 * H0c));
    float s = O[(size_t)bc * Nn + (i >> 2) * Hh + jg];
    float4 pack = make_float4(s, s, s, s);
    *(float4*)(out + ((size_t)bc * H0c + i) * H0c + jg * 4) = pack;
}

extern "C" void kernel_launch(void* const* d_in, const int* in_sizes, int n_in,
                              void* d_out, int out_size, void* d_ws, size_t ws_size,
                              hipStream_t stream) {
    (void)in_sizes; (void)n_in; (void)out_size; (void)ws_size;
    fp x     = (fp)d_in[0];
    fp q_w   = (fp)d_in[1];
    fp q_b   = (fp)d_in[2];
    fp kv_w  = (fp)d_in[3];
    fp kv_b  = (fp)d_in[4];
    fp sr1_w = (fp)d_in[5];
    fp bn1_g = (fp)d_in[6];
    fp bn1_b = (fp)d_in[7];
    fp bn1_m = (fp)d_in[8];
    fp bn1_v = (fp)d_in[9];
    fp sr2_w = (fp)d_in[10];
    fp bn2_g = (fp)d_in[11];
    fp bn2_b = (fp)d_in[12];
    fp bn2_m = (fp)d_in[13];
    fp bn2_v = (fp)d_in[14];
    fp lc_w  = (fp)d_in[15];
    fp lc_b  = (fp)d_in[16];
    float* out = (float*)d_out;

    // workspace layout (floats), with aliasing; peak 13.28M f32 = 53.1 MB
    float* ws   = (float*)d_ws;
    float* xds  = ws;                                   // B*C*N   (dead after k_sr1/q-gemm)
    float* qbuf = xds  + (size_t)Bsz * Cc * Nn;         // B*C*N
    float* kv1  = qbuf + (size_t)Bsz * Cc * Nn;         // B*C*Ms  (dead after sr2-gemm)
    float* kv2  = kv1  + (size_t)Bsz * Cc * Ms;         // B*C*Ms  (dead after k_lc)
    float* kv3  = kv2  + (size_t)Bsz * Cc * Ms;         // B*C*Ms
    float* kvp  = kv1;                                  // B*2C*Ms aliases kv1+kv2
    float* Obuf = xds;                                  // B*C*N   aliases xds

    k_downsample<<<Bsz * Cc * Nn / 256, 256, 0, stream>>>(x, xds);
    k_gemm<<<dim3(18, 4, Bsz), 256, 0, stream>>>(q_w, xds, qbuf, Cc, Nn,
                                                 q_b, nullptr, nullptr, nullptr, nullptr);
    k_sr1<<<Bsz * Cc * Ms / 256, 256, 0, stream>>>(xds, sr1_w, bn1_g, bn1_b, bn1_m, bn1_v, kv1);
    k_gemm<<<dim3(5, 4, Bsz), 256, 0, stream>>>(sr2_w, kv1, kv2, Cc, Ms,
                                                nullptr, bn2_g, bn2_b, bn2_m, bn2_v);
    k_lc<<<Bsz * Cc * Ms / 256, 256, 0, stream>>>(kv2, lc_w, lc_b, kv3);
    k_gemm<<<dim3(5, 8, Bsz), 256, 0, stream>>>(kv_w, kv3, kvp, C2, Ms,
                                                kv_b, nullptr, nullptr, nullptr, nullptr);
    k_attn<<<dim3(Nn / 64, Bsz * HNh), 256, 0, stream>>>(qbuf, kvp, Obuf);
    k_upsample<<<(unsigned)((size_t)Bsz * Cc * H0c * 48 / 256), 256, 0, stream>>>(Obuf, out);
}

// Round 4
// 648.493 us; speedup vs baseline: 1.8637x; 1.8637x over previous
//
#include <hip/hip_runtime.h>

// Problem constants (fixed by setup_inputs)
#define Bsz 4
#define Cc  512
#define C2  1024
#define H0c 192
#define Hh  48
#define Nn  2304   // 48*48
#define HNh 8
#define HD  64
#define Hs  25
#define Ms  625    // 25*25

typedef const float* fp;
typedef _Float16 f16;
typedef __attribute__((ext_vector_type(8))) _Float16 f16x8;
typedef __attribute__((ext_vector_type(4))) _Float16 f16x4;
typedef __attribute__((ext_vector_type(4))) float    f32x4;

// ---------------- K1: stride-4 nearest downsample ----------------
__global__ __launch_bounds__(256) void k_downsample(fp __restrict__ x,
                                                    float* __restrict__ xds) {
    int idx = blockIdx.x * 256 + threadIdx.x;            // < B*C*2304
    if (idx >= Bsz * Cc * Nn) return;
    int j  = idx % Hh;
    int i  = (idx / Hh) % Hh;
    int bc = idx / Nn;
    xds[idx] = x[((size_t)bc * H0c + i * 4) * H0c + j * 4];
}

// ---------------- transpose: f32 [R][S] (S-contig) -> f16 [S][R] (R-contig) ----------------
__global__ __launch_bounds__(256) void k_transpose(const float* __restrict__ in,
                                                   f16* __restrict__ out,
                                                   int R, int S,
                                                   size_t in_bs, size_t out_bs) {
    __shared__ float tile[32][33];
    const float* inb = in + (size_t)blockIdx.z * in_bs;
    f16* outb = out + (size_t)blockIdx.z * out_bs;
    int s0 = blockIdx.x * 32, r0 = blockIdx.y * 32;
    int t = threadIdx.x;
    #pragma unroll
    for (int p = 0; p < 4; p++) {
        int e = t + p * 256; int i = e >> 5, j = e & 31;
        float v = 0.f;
        if (r0 + i < R && s0 + j < S) v = inb[(size_t)(r0 + i) * S + s0 + j];
        tile[i][j] = v;
    }
    __syncthreads();
    #pragma unroll
    for (int p = 0; p < 4; p++) {
        int e = t + p * 256; int oi = e >> 5, oj = e & 31;
        if (s0 + oi < S && r0 + oj < R)
            outb[(size_t)(s0 + oi) * R + r0 + oj] = (f16)tile[oj][oi];
    }
}

// ---------------- MFMA GEMM: Y[b][o][n] = sum_c W[o][c] * Xt[b][n][c] ----------------
// W f32 [Md][512] (k-contig). Xt f16 [b][Nd][512] (k-contig rows).
// mode 0: Yf f32 [b][Md][Nd], epilogue (bias?, BN?)
// mode 1: Yt f16 [(b*8+h)][NtRows][64] per-head transposed (+bias)
// mode 2: o<512 -> mode1 path into Yt; o>=512 -> f32 into Yf [b][512][Nd] (+bias)
__global__ __launch_bounds__(256) void k_gemm_mfma(
    const float* __restrict__ W, const f16* __restrict__ Xt,
    float* __restrict__ Yf, f16* __restrict__ Yt,
    const int Md, const int Nd, const int NtRows, const int mode,
    fp __restrict__ bias,
    fp __restrict__ bn_g, fp __restrict__ bn_b, fp __restrict__ bn_m, fp __restrict__ bn_v)
{
    __shared__ f16 sA[128 * 80];   // [m][k], stride 80 (160B rows: 16B-aligned, bank-balanced)
    __shared__ f16 sB[128 * 80];   // [n][k]
    const int b  = blockIdx.z;
    const int m0 = blockIdx.y * 128, n0 = blockIdx.x * 128;
    const int t = threadIdx.x;
    const int lane = t & 63, w = t >> 6;
    const int lm = lane & 15, q = lane >> 4;
    const int wm = w >> 1, wn = w & 1;
    const f16* Xb = Xt + (size_t)b * Nd * 512;

    f32x4 acc[4][4];
    #pragma unroll
    for (int i = 0; i < 4; i++)
        #pragma unroll
        for (int j = 0; j < 4; j++)
            #pragma unroll
            for (int r = 0; r < 4; r++) acc[i][j][r] = 0.f;

    for (int k0 = 0; k0 < 512; k0 += 64) {
        {   // stage A (W f32 -> f16), 128 rows x 64 k
            int r = t >> 1, hh = (t & 1) * 32;
            const float* wr = W + (size_t)(m0 + r) * 512 + k0 + hh;
            f16* dst = &sA[r * 80 + hh];
            #pragma unroll
            for (int i = 0; i < 8; i++) {
                float4 v = *(const float4*)&wr[i * 4];
                f16x4 h4; h4[0] = (f16)v.x; h4[1] = (f16)v.y; h4[2] = (f16)v.z; h4[3] = (f16)v.w;
                *(f16x4*)&dst[i * 4] = h4;
            }
        }
        {   // stage B (Xt f16), 128 n-rows x 64 k
            int r = t >> 1, hh = (t & 1) * 32;
            bool ok = (n0 + r) < Nd;
            const f16* xr = Xb + (size_t)(n0 + r) * 512 + k0 + hh;
            f16* dst = &sB[r * 80 + hh];
            #pragma unroll
            for (int i = 0; i < 4; i++) {
                f16x8 v;
                if (ok) {
                    v = *(const f16x8*)&xr[i * 8];
                } else {
                    for (int z = 0; z < 8; z++) v[z] = (f16)0.f;
                }
                *(f16x8*)&dst[i * 8] = v;
            }
        }
        __syncthreads();
        #pragma unroll
        for (int ks = 0; ks < 2; ks++) {
            f16x8 af[4], bf[4];
            #pragma unroll
            for (int i = 0; i < 4; i++)
                af[i] = *(const f16x8*)&sA[(wm * 64 + i * 16 + lm) * 80 + ks * 32 + q * 8];
            #pragma unroll
            for (int j = 0; j < 4; j++)
                bf[j] = *(const f16x8*)&sB[(wn * 64 + j * 16 + lm) * 80 + ks * 32 + q * 8];
            #pragma unroll
            for (int i = 0; i < 4; i++)
                #pragma unroll
                for (int j = 0; j < 4; j++)
                    acc[i][j] = __builtin_amdgcn_mfma_f32_16x16x32_f16(af[i], bf[j], acc[i][j], 0, 0, 0);
        }
        __syncthreads();
    }

    // epilogue: D layout col=lane&15 (n), row=q*4+reg (o)
    #pragma unroll
    for (int i = 0; i < 4; i++) {
        int ob = m0 + wm * 64 + i * 16 + q * 4;       // + reg
        float badd[4], bsc[4], bsh[4];
        #pragma unroll
        for (int r = 0; r < 4; r++) {
            int o = ob + r;
            badd[r] = bias ? bias[o] : 0.f;
            if (bn_g) { bsc[r] = bn_g[o] * rsqrtf(bn_v[o] + 1e-5f); bsh[r] = bn_b[o] - bn_m[o] * bsc[r]; }
            else      { bsc[r] = 1.f; bsh[r] = 0.f; }
        }
        #pragma unroll
        for (int j = 0; j < 4; j++) {
            int n = n0 + wn * 64 + j * 16 + lm;
            if (n >= Nd) continue;
            f32x4 a = acc[i][j];
            if (mode == 0) {
                #pragma unroll
                for (int r = 0; r < 4; r++)
                    Yf[((size_t)b * Md + ob + r) * Nd + n] = (a[r] + badd[r]) * bsc[r] + bsh[r];
            } else if (mode == 1 || (mode == 2 && ob < 512)) {
                f16x4 h;
                #pragma unroll
                for (int r = 0; r < 4; r++) h[r] = (f16)(a[r] + badd[r]);
                int hh = ob >> 6, d0 = ob & 63;
                *(f16x4*)&Yt[((size_t)(b * 8 + hh) * NtRows + n) * 64 + d0] = h;
            } else { // mode 2, v-half -> f32 natural layout
                #pragma unroll
                for (int r = 0; r < 4; r++)
                    Yf[((size_t)b * 512 + (ob + r - 512)) * Nd + n] = a[r] + badd[r];
            }
        }
    }
}

// ---------------- K3: 2x2 dwconv s2 p1 + BN + ReLU ----------------
__global__ __launch_bounds__(256) void k_sr1(const float* __restrict__ xds, fp __restrict__ w,
                                             fp g, fp bb, fp bm, fp bv,
                                             float* __restrict__ kv1) {
    int idx = blockIdx.x * 256 + threadIdx.x;    // < B*C*625
    if (idx >= Bsz * Cc * Ms) return;
    int wo = idx % Hs, ho = (idx / Hs) % Hs, bc = idx / Ms;
    int c = bc % Cc;
    const float* src = xds + (size_t)bc * Nn;
    float acc = 0.f;
    #pragma unroll
    for (int di = 0; di < 2; di++) {
        int ih = ho * 2 - 1 + di;
        if (ih < 0 || ih >= Hh) continue;
        #pragma unroll
        for (int dj = 0; dj < 2; dj++) {
            int iw = wo * 2 - 1 + dj;
            if (iw < 0 || iw >= Hh) continue;
            acc += w[c * 4 + di * 2 + dj] * src[ih * Hh + iw];
        }
    }
    float sc = g[c] * rsqrtf(bv[c] + 1e-5f);
    float y = (acc - bm[c]) * sc + bb[c];
    kv1[idx] = fmaxf(y, 0.f);
}

// ---------------- K5: 3x3 dwconv s1 p1 + bias + residual ----------------
__global__ __launch_bounds__(256) void k_lc(const float* __restrict__ kv2, fp __restrict__ w,
                                            fp __restrict__ lb, float* __restrict__ kv3) {
    int idx = blockIdx.x * 256 + threadIdx.x;    // < B*C*625
    if (idx >= Bsz * Cc * Ms) return;
    int wo = idx % Hs, ho = (idx / Hs) % Hs, bc = idx / Ms;
    int c = bc % Cc;
    const float* src = kv2 + (size_t)bc * Ms;
    float acc = 0.f;
    #pragma unroll
    for (int di = 0; di < 3; di++) {
        int ih = ho - 1 + di;
        if (ih < 0 || ih >= Hs) continue;
        #pragma unroll
        for (int dj = 0; dj < 3; dj++) {
            int iw = wo - 1 + dj;
            if (iw < 0 || iw >= Hs) continue;
            acc += w[c * 9 + di * 3 + dj] * src[ih * Hs + iw];
        }
    }
    kv3[idx] = acc + lb[c] + src[ho * Hs + wo];
}

// ---------------- cvt: vbuf f32 [b][512][625] -> vt f16 [b*512][640] (zero-pad cols) --------
__global__ __launch_bounds__(256) void k_cvtv(const float* __restrict__ vbuf,
                                              f16* __restrict__ vt) {
    int idx = blockIdx.x * 256 + threadIdx.x;    // < 4*512*640
    if (idx >= Bsz * Cc * 640) return;
    int col = idx % 640, row = idx / 640;
    vt[idx] = (f16)((col < Ms) ? vbuf[(size_t)row * Ms + col] : 0.f);
}

// ---------------- MFMA flash attention ----------------
// Qt f16 [bh][2304][64]; Kt f16 [bh][640][64] (rows>=625 garbage, masked);
// Vt f16 [bh*64 + d][640] (cols>=625 zero)  ->  Obuf f32 [b][512][2304]
__global__ __launch_bounds__(256) void k_attn_mfma(
    const f16* __restrict__ Qt, const f16* __restrict__ Kt,
    const f16* __restrict__ Vt, float* __restrict__ Obuf)
{
    __shared__ f16 sK[64 * 80];       // [key][d]
    __shared__ f16 sV[64 * 80];       // [d][key]
    __shared__ f16 sP[4][16 * 80];    // per-wave [qrow][key]

    int bh = blockIdx.y;
    int n0 = blockIdx.x * 64;
    int t = threadIdx.x, w = t >> 6, lane = t & 63;
    int lm = lane & 15, q = lane >> 4;
    f16* sPw = &sP[w][0];

    // Q fragments (held in registers across all chunks)
    f16x8 qf[2];
    {
        const f16* qrow = Qt + ((size_t)bh * Nn + n0 + w * 16 + lm) * 64;
        qf[0] = *(const f16x8*)&qrow[q * 8];
        qf[1] = *(const f16x8*)&qrow[32 + q * 8];
    }

    f32x4 od[4];
    #pragma unroll
    for (int dt = 0; dt < 4; dt++)
        #pragma unroll
        for (int r = 0; r < 4; r++) od[dt][r] = 0.f;
    float mold[4], lold[4];
    #pragma unroll
    for (int r = 0; r < 4; r++) { mold[r] = -1e30f; lold[r] = 0.f; }

    int kr = t >> 2, kc = t & 3;
    const f16* kbase = Kt + (size_t)bh * 640 * 64;
    const f16* vbase = Vt + (size_t)bh * 64 * 640;

    for (int mc = 0; mc < 640; mc += 64) {
        {   // stage K [key][d] and V [d][key]
            const f16* ksrc = kbase + (size_t)(mc + kr) * 64;
            *(f16x8*)&sK[kr * 80 + kc * 8]      = *(const f16x8*)&ksrc[kc * 8];
            *(f16x8*)&sK[kr * 80 + 32 + kc * 8] = *(const f16x8*)&ksrc[32 + kc * 8];
            const f16* vsrc = vbase + (size_t)kr * 640 + mc;
            *(f16x8*)&sV[kr * 80 + kc * 8]      = *(const f16x8*)&vsrc[kc * 8];
            *(f16x8*)&sV[kr * 80 + 32 + kc * 8] = *(const f16x8*)&vsrc[32 + kc * 8];
        }
        __syncthreads();

        // scores S = Q K^T : A=Q[qrow][d], B=K^T[d][key]
        f32x4 sc4[4];
        #pragma unroll
        for (int j = 0; j < 4; j++)
            #pragma unroll
            for (int r = 0; r < 4; r++) sc4[j][r] = 0.f;
        #pragma unroll
        for (int ks = 0; ks < 2; ks++) {
            #pragma unroll
            for (int j = 0; j < 4; j++) {
                f16x8 kf = *(const f16x8*)&sK[(j * 16 + lm) * 80 + ks * 32 + q * 8];
                sc4[j] = __builtin_amdgcn_mfma_f32_16x16x32_f16(qf[ks], kf, sc4[j], 0, 0, 0);
            }
        }

        // online softmax; row r = q*4+reg, cols j*16+lm
        #pragma unroll
        for (int reg = 0; reg < 4; reg++) {
            float mx = -1e30f;
            #pragma unroll
            for (int j = 0; j < 4; j++) {
                float s = sc4[j][reg] * 0.125f;
                if (mc + j * 16 + lm >= Ms) s = -1e30f;
                sc4[j][reg] = s;
                mx = fmaxf(mx, s);
            }
            #pragma unroll
            for (int off = 1; off < 16; off <<= 1) mx = fmaxf(mx, __shfl_xor(mx, off));
            float mnew = fmaxf(mold[reg], mx);
            float alpha = __expf(mold[reg] - mnew);
            float rs = 0.f;
            #pragma unroll
            for (int j = 0; j < 4; j++) {
                float p = __expf(sc4[j][reg] - mnew);
                sc4[j][reg] = p;
                rs += p;
            }
            #pragma unroll
            for (int off = 1; off < 16; off <<= 1) rs += __shfl_xor(rs, off);
            lold[reg] = lold[reg] * alpha + rs;
            mold[reg] = mnew;
            #pragma unroll
            for (int dt = 0; dt < 4; dt++) od[dt][reg] *= alpha;
            #pragma unroll
            for (int j = 0; j < 4; j++)
                sPw[(q * 4 + reg) * 80 + j * 16 + lm] = (f16)sc4[j][reg];
        }

        // O += P V : A=P[qrow][key], B=V^T[key][d] (sV holds [d][key])
        #pragma unroll
        for (int ks = 0; ks < 2; ks++) {
            f16x8 pa = *(const f16x8*)&sPw[lm * 80 + ks * 32 + q * 8];
            #pragma unroll
            for (int dt = 0; dt < 4; dt++) {
                f16x8 vf = *(const f16x8*)&sV[(dt * 16 + lm) * 80 + ks * 32 + q * 8];
                od[dt] = __builtin_amdgcn_mfma_f32_16x16x32_f16(pa, vf, od[dt], 0, 0, 0);
            }
        }
        __syncthreads();
    }

    float inv[4];
    #pragma unroll
    for (int r = 0; r < 4; r++) inv[r] = 1.f / lold[r];
    #pragma unroll
    for (int dt = 0; dt < 4; dt++) {
        f32x4 o;
        #pragma unroll
        for (int r = 0; r < 4; r++) o[r] = od[dt][r] * inv[r];
        size_t c = (size_t)bh * 64 + dt * 16 + lm;     // = b*512 + h*64 + d
        *(f32x4*)&Obuf[c * Nn + n0 + w * 16 + q * 4] = o;
    }
}

// ---------------- K8: 4x nearest upsample, float4 stores ----------------
__global__ __launch_bounds__(256) void k_upsample(const float* __restrict__ O,
                                                  float* __restrict__ out) {
    size_t idx = (size_t)blockIdx.x * 256 + threadIdx.x;   // < B*C*192*48
    if (idx >= (size_t)Bsz * Cc * H0c * 48) return;
    int jg = (int)(idx % 48);
    int i  = (int)((idx / 48) % H0c);
    int bc = (int)(idx / ((size_t)48 * H0c));
    float s = O[(size_t)bc * Nn + (i >> 2) * Hh + jg];
    float4 pack = make_float4(s, s, s, s);
    *(float4*)(out + ((size_t)bc * H0c + i) * H0c + jg * 4) = pack;
}

extern "C" void kernel_launch(void* const* d_in, const int* in_sizes, int n_in,
                              void* d_out, int out_size, void* d_ws, size_t ws_size,
                              hipStream_t stream) {
    (void)in_sizes; (void)n_in; (void)out_size; (void)ws_size;
    fp x     = (fp)d_in[0];
    fp q_w   = (fp)d_in[1];
    fp q_b   = (fp)d_in[2];
    fp kv_w  = (fp)d_in[3];
    fp kv_b  = (fp)d_in[4];
    fp sr1_w = (fp)d_in[5];
    fp bn1_g = (fp)d_in[6];
    fp bn1_b = (fp)d_in[7];
    fp bn1_m = (fp)d_in[8];
    fp bn1_v = (fp)d_in[9];
    fp sr2_w = (fp)d_in[10];
    fp bn2_g = (fp)d_in[11];
    fp bn2_b = (fp)d_in[12];
    fp bn2_m = (fp)d_in[13];
    fp bn2_v = (fp)d_in[14];
    fp lc_w  = (fp)d_in[15];
    fp lc_b  = (fp)d_in[16];
    float* out = (float*)d_out;

    // workspace layout (f32 slots), peak 12.67M f32 = 50.7 MB (<= proven-available 53.1 MB)
    float* ws   = (float*)d_ws;
    float* A    = ws;                         // 4,718,592 f32
    float* xds  = A;                          //   xds: dead after k_sr1 / xt-transpose
    float* Obuf = A;                          //   Obuf: written by attn (xds,kv3 dead by then)
    float* kv3  = A + 3400000;                //   1,280,000 f32, lc->kv3t window only
    float* Bv   = A + 4718592;                // 2,359,296 f32
    f16*   xt   = (f16*)Bv;                   //   xt: dead after q-gemm
    float* kv2  = Bv;                         //   kv2: written by sr2-gemm (xt dead)
    float* Cq   = Bv + 2359296;               // 2,359,296 f32
    f16*   Qt   = (f16*)Cq;
    float* Dv   = Cq + 2359296;               // 1,280,000 f32
    float* kv1  = Dv;                         //   kv1: dead after kv1t-transpose
    float* vbuf = Dv;                         //   vbuf: written by kv-gemm (kv1 dead)
    float* Ev   = Dv + 1280000;               // 640,000 f32 (1.28M f16)
    f16*   kv1t = (f16*)Ev;                   //   dead after sr2-gemm
    f16*   kv3t = (f16*)Ev;                   //   written after lc
    float* Fv   = Ev + 640000;                // 655,360 f32
    f16*   Kt   = (f16*)Fv;                   //   [32][640][64] f16
    float* Gv   = Fv + 655360;                // 655,360 f32
    f16*   vt   = (f16*)Gv;                   //   [2048][640] f16

    k_downsample<<<Bsz * Cc * Nn / 256, 256, 0, stream>>>(x, xds);
    k_transpose<<<dim3(72, 16, Bsz), 256, 0, stream>>>(xds, xt, Cc, Nn,
                                                       (size_t)Cc * Nn, (size_t)Nn * Cc);
    k_gemm_mfma<<<dim3(18, 4, Bsz), 256, 0, stream>>>(q_w, xt, nullptr, Qt,
        Cc, Nn, Nn, 1, q_b, nullptr, nullptr, nullptr, nullptr);
    k_sr1<<<Bsz * Cc * Ms / 256, 256, 0, stream>>>(xds, sr1_w, bn1_g, bn1_b, bn1_m, bn1_v, kv1);
    k_transpose<<<dim3(20, 16, Bsz), 256, 0, stream>>>(kv1, kv1t, Cc, Ms,
                                                       (size_t)Cc * Ms, (size_t)Ms * Cc);
    k_gemm_mfma<<<dim3(5, 4, Bsz), 256, 0, stream>>>(sr2_w, kv1t, kv2, nullptr,
        Cc, Ms, 0, 0, nullptr, bn2_g, bn2_b, bn2_m, bn2_v);
    k_lc<<<Bsz * Cc * Ms / 256, 256, 0, stream>>>(kv2, lc_w, lc_b, kv3);
    k_transpose<<<dim3(20, 16, Bsz), 256, 0, stream>>>(kv3, kv3t, Cc, Ms,
                                                       (size_t)Cc * Ms, (size_t)Ms * Cc);
    k_gemm_mfma<<<dim3(5, 8, Bsz), 256, 0, stream>>>(kv_w, kv3t, vbuf, Kt,
        C2, Ms, 640, 2, kv_b, nullptr, nullptr, nullptr, nullptr);
    k_cvtv<<<Bsz * Cc * 640 / 256, 256, 0, stream>>>(vbuf, vt);
    k_attn_mfma<<<dim3(Nn / 64, Bsz * HNh), 256, 0, stream>>>(Qt, Kt, vt, Obuf);
    k_upsample<<<(unsigned)((size_t)Bsz * Cc * H0c * 48 / 256), 256, 0, stream>>>(Obuf, out);
}